// Round 7
// baseline (103.816 us; speedup 1.0000x reference)
//
#include <hip/hip_runtime.h>
#include <stdint.h>

typedef int i32x4 __attribute__((ext_vector_type(4)));
typedef float f32x4 __attribute__((ext_vector_type(4)));

#define N_IMG 32
#define C_IN 256
#define H_IN 56
#define W_IN 56
#define K_OUT 256
#define H_OUT 54
#define W_OUT 54
#define HW_OUT 2916          // 54*54
#define M_PIX 93312          // 32*2916 = 192 * 486
#define CHW_OUT 746496       // 256*2916

#define BM 192               // pixel rows per block (grid 486)

#define XT_BYTES ((size_t)N_IMG * H_IN * W_IN * C_IN)   // 25,690,112 (i8 NHWC)
#define WT_BYTES ((size_t)9 * K_OUT * C_IN)             // 589,824   (i8 [tap][k][c])

// LDS: halo 448 rows x 128 B = 57344 @0 ; B triple buffer 3 x 32768 @57344
// total 155648 <= 163840
#define HALO_BYTES 57344
#define B_STRIDE 32768

// -------- fused transforms: x NCHW i32 -> NHWC i8 ; w OIHW f32 -> [tap][k][c] i8 ----
__global__ __launch_bounds__(256) void xform(const int* __restrict__ x,
                                             const float* __restrict__ w,
                                             unsigned char* __restrict__ xt,
                                             unsigned char* __restrict__ wt) {
    const int bid = blockIdx.x;
    if (bid < N_IMG * H_IN) {
        const int n = bid / H_IN;
        const int h = bid % H_IN;
        const int c = threadIdx.x;
        const int* src = x + ((size_t)((n * C_IN + c) * H_IN + h)) * W_IN;
        unsigned char* dst = xt + ((size_t)(n * H_IN + h) * W_IN) * C_IN + c;
        #pragma unroll
        for (int w0 = 0; w0 < W_IN; w0 += 4) {
            int4 v = *(const int4*)(src + w0);
            int a[4] = {v.x, v.y, v.z, v.w};
            #pragma unroll
            for (int j = 0; j < 4; ++j) {
                int q = a[j] < 0 ? 0 : (a[j] > 7 ? 7 : a[j]);
                dst[(size_t)(w0 + j) * C_IN] = (unsigned char)q;
            }
        }
    } else {
        const int k = bid - N_IMG * H_IN;
        const int c = threadIdx.x;
        const float* src = w + ((size_t)k * C_IN + c) * 9;
        #pragma unroll
        for (int rs = 0; rs < 9; ++rs) {
            int iv = (int)src[rs];   // truncation == astype(int32); values 0..6
            wt[((size_t)rs * K_OUT + k) * C_IN + c] = (unsigned char)iv;
        }
    }
}

// -------- async global->LDS (width 16) --------
__device__ __forceinline__ void gload_lds16(const void* g, void* l) {
    __builtin_amdgcn_global_load_lds(
        (const __attribute__((address_space(1))) uint32_t*)g,
        (__attribute__((address_space(3))) uint32_t*)l,
        16, 0, 0);
}

__device__ __forceinline__ unsigned lds_off(const void* p) {
    return (unsigned)(unsigned long long)(__attribute__((address_space(3))) const char*)p;
}

#define DSREAD(dst, addr) \
    asm volatile("ds_read_b128 %0, %1" : "=v"(dst) : "v"(addr))
#define BAR __builtin_amdgcn_s_barrier()
#define LGKM0 do { asm volatile("s_waitcnt lgkmcnt(0)" ::: "memory"); \
                   __builtin_amdgcn_sched_barrier(0); } while (0)

// -------- main conv (i8): BM=192 pix, BN=256 ch, BK=128; halo-A + B triple-buf ----
// 8 waves (2M x 4N), per-wave 96x64 (acc 6x4, R4-proven addressing).
// 18 K-tiles (h-major: t=0..8 -> ch-half 0 taps 0..8; t=9..17 -> ch-half 1).
// Per tile: 4 fine phases; B(t+2) staged 1 gload/phase; vmcnt(4) at tile end.
__global__ __launch_bounds__(512, 2) void conv_mfma(const unsigned char* __restrict__ xt,
                                                    const unsigned char* __restrict__ wt,
                                                    float* __restrict__ out) {
    __shared__ __align__(16) unsigned char lds[155648];

    const int t512 = threadIdx.x;
    const int l    = t512 & 63;
    const int wid  = t512 >> 6;
    const int wr   = wid >> 2;     // 0..1 -> 96-pixel half
    const int wc   = wid & 3;      // 0..3 -> 64-channel quarter
    const int mb   = blockIdx.x;   // 486 M-tiles

    // staging thread geometry: 128-B rows, 8 slots of 16 B; both-sides swizzle
    const int slot = t512 & 7;
    const int srow = t512 >> 3;                    // 0..63 within an 8 KB round
    const int cs   = ((slot ^ (srow & 7)) << 4);   // data chunk = slot ^ (row&7)
    const int tb16 = t512 * 16;
    const int sb   = srow * 256 + cs;              // per-thread src base (256 B/row)

    // block-base input pixel
    const int m0  = mb * BM;
    const int n0  = m0 / HW_OUT;
    const int rm0 = m0 - n0 * HW_OUT;
    const int oh0 = rm0 / W_OUT;
    const int ow0 = rm0 - oh0 * W_OUT;
    const int pix0 = n0 * (H_IN * W_IN) + oh0 * W_IN + ow0;

    // per-lane halo row deltas for the 6 M-fragments (exact mapping; max 424 < 448)
    const int lrow = l & 15;
    int drow[6];
    #pragma unroll
    for (int mf = 0; mf < 6; ++mf) {
        const int m   = m0 + wr * 96 + mf * 16 + lrow;
        const int n   = m / HW_OUT;
        const int rem = m - n * HW_OUT;
        const int oh  = rem / W_OUT;
        const int ow  = rem - oh * W_OUT;
        drow[mf] = n * (H_IN * W_IN) + oh * W_IN + ow - pix0;
    }

    const int g16 = (l >> 4) << 4;                       // 0/16/32/48
    const unsigned ck[2] = { (unsigned)g16, (unsigned)(64 + g16) };
    const unsigned swzB = (unsigned)((lrow & 7) << 4);
    unsigned boffk[4][2];
    #pragma unroll
    for (int nf = 0; nf < 4; ++nf) {
        const unsigned rb = (unsigned)((wc * 64 + nf * 16 + lrow) << 7);
        boffk[nf][0] = rb + (ck[0] ^ swzB);
        boffk[nf][1] = rb + (ck[1] ^ swzB);
    }

    i32x4 acc[6][4];
    #pragma unroll
    for (int i = 0; i < 6; ++i)
        #pragma unroll
        for (int j = 0; j < 4; ++j)
            acc[i][j] = (i32x4){0, 0, 0, 0};

    const char* xb = (const char*)xt;
    const char* wb = (const char*)wt;
    const unsigned ldsb = lds_off(lds);

    // 7 gloads: halo rows 0..447 of ch-half H (OOB rows land in wt region: harmless)
    #define STAGE_HALO(H) do {                                               \
        const char* hs_ = xb + (size_t)pix0 * 256 + (H) * 128 + sb;          \
        _Pragma("unroll")                                                    \
        for (int i_ = 0; i_ < 7; ++i_)                                       \
            gload_lds16(hs_ + (size_t)i_ * 16384, lds + i_ * 8192 + tb16);   \
    } while (0)

    // full B tile for K-tile T into buf T%3 (prologue only)
    #define STAGE_B4(T) do {                                                 \
        const int h_ = (T) >= 9, tp_ = (T) - (h_ ? 9 : 0);                   \
        const char* bs_ = wb + tp_ * 65536 + h_ * 128 + sb;                  \
        unsigned char* bd_ = lds + HALO_BYTES + ((T) % 3) * B_STRIDE + tb16; \
        _Pragma("unroll")                                                    \
        for (int p_ = 0; p_ < 4; ++p_)                                       \
            gload_lds16(bs_ + p_ * 16384, bd_ + p_ * 8192);                  \
    } while (0)

    // ---- prologue: halo(0), B(0)->buf0, B(1)->buf1; drain halo+B(0) only ----
    STAGE_HALO(0);
    STAGE_B4(0);
    STAGE_B4(1);
    asm volatile("s_waitcnt vmcnt(4)" ::: "memory");   // B(1)'s 4 stay in flight
    BAR;

    unsigned o0 = 0, o1 = B_STRIDE, o2 = 2 * B_STRIDE;   // cur / next / stage

    for (int t = 0; t < 18; ++t) {
        const int h    = (t >= 9);
        const int tap  = t - (h ? 9 : 0);
        const int r    = tap / 3;
        const int s    = tap - r * 3;
        const int toff = r * W_IN + s;                 // pixel offset within halo
        const int t2   = t + 2;
        const bool stg = (t2 < 18);
        const int h2   = (t2 >= 9);
        const int tap2 = t2 - (h2 ? 9 : 0);
        const char* bsrc2 = wb + tap2 * 65536 + h2 * 128 + sb;
        unsigned char* bdst2 = lds + HALO_BYTES + tb16;   // + o2 at use
        const unsigned bB = ldsb + HALO_BYTES + o0;

        i32x4 av[3], bv[4];

        // ---------- phase 1: A[0..2] kk0 + B[0..3] kk0, stage rnd0, 12 MFMA ----
        #pragma unroll
        for (int i = 0; i < 3; ++i) {
            const int row = drow[i] + toff;
            DSREAD(av[i], ldsb + ((unsigned)row << 7) + (ck[0] ^ ((unsigned)(row & 7) << 4)));
        }
        #pragma unroll
        for (int nf = 0; nf < 4; ++nf) DSREAD(bv[nf], bB + boffk[nf][0]);
        if (stg) gload_lds16(bsrc2, bdst2 + o2);
        BAR; LGKM0;
        __builtin_amdgcn_s_setprio(1);
        #pragma unroll
        for (int i = 0; i < 3; ++i)
            #pragma unroll
            for (int nf = 0; nf < 4; ++nf)
                acc[i][nf] = __builtin_amdgcn_mfma_i32_16x16x64_i8(av[i], bv[nf], acc[i][nf], 0, 0, 0);
        __builtin_amdgcn_s_setprio(0);
        BAR;

        // ---------- phase 2: A[3..5] kk0, stage rnd1, 12 MFMA ----------
        #pragma unroll
        for (int i = 0; i < 3; ++i) {
            const int row = drow[3 + i] + toff;
            DSREAD(av[i], ldsb + ((unsigned)row << 7) + (ck[0] ^ ((unsigned)(row & 7) << 4)));
        }
        if (stg) gload_lds16(bsrc2 + 16384, bdst2 + o2 + 8192);
        BAR; LGKM0;
        __builtin_amdgcn_s_setprio(1);
        #pragma unroll
        for (int i = 0; i < 3; ++i)
            #pragma unroll
            for (int nf = 0; nf < 4; ++nf)
                acc[3 + i][nf] = __builtin_amdgcn_mfma_i32_16x16x64_i8(av[i], bv[nf], acc[3 + i][nf], 0, 0, 0);
        __builtin_amdgcn_s_setprio(0);
        BAR;

        // ---------- phase 3: A[0..2] kk1 + B[0..3] kk1, stage rnd2, 12 MFMA ----
        #pragma unroll
        for (int i = 0; i < 3; ++i) {
            const int row = drow[i] + toff;
            DSREAD(av[i], ldsb + ((unsigned)row << 7) + (ck[1] ^ ((unsigned)(row & 7) << 4)));
        }
        #pragma unroll
        for (int nf = 0; nf < 4; ++nf) DSREAD(bv[nf], bB + boffk[nf][1]);
        if (stg) gload_lds16(bsrc2 + 32768, bdst2 + o2 + 16384);
        BAR; LGKM0;
        __builtin_amdgcn_s_setprio(1);
        #pragma unroll
        for (int i = 0; i < 3; ++i)
            #pragma unroll
            for (int nf = 0; nf < 4; ++nf)
                acc[i][nf] = __builtin_amdgcn_mfma_i32_16x16x64_i8(av[i], bv[nf], acc[i][nf], 0, 0, 0);
        __builtin_amdgcn_s_setprio(0);
        BAR;

        // ---------- phase 4: A[3..5] kk1, stage rnd3, 12 MFMA ----------
        #pragma unroll
        for (int i = 0; i < 3; ++i) {
            const int row = drow[3 + i] + toff;
            DSREAD(av[i], ldsb + ((unsigned)row << 7) + (ck[1] ^ ((unsigned)(row & 7) << 4)));
        }
        if (stg) gload_lds16(bsrc2 + 49152, bdst2 + o2 + 24576);
        BAR; LGKM0;
        __builtin_amdgcn_s_setprio(1);
        #pragma unroll
        for (int i = 0; i < 3; ++i)
            #pragma unroll
            for (int nf = 0; nf < 4; ++nf)
                acc[3 + i][nf] = __builtin_amdgcn_mfma_i32_16x16x64_i8(av[i], bv[nf], acc[3 + i][nf], 0, 0, 0);
        __builtin_amdgcn_s_setprio(0);

        // ---------- tile end: counted vmcnt; halo restage at h boundary ----------
        if (t == 8) {
            BAR;                       // all halo(0) reads complete
            STAGE_HALO(1);
            asm volatile("s_waitcnt vmcnt(0)" ::: "memory");
            BAR;
        } else if (t == 16) {
            asm volatile("s_waitcnt vmcnt(0)" ::: "memory");   // drain B(17)
            BAR;
        } else if (t < 16) {
            asm volatile("s_waitcnt vmcnt(4)" ::: "memory");   // B(t+1) resident; B(t+2) in flight
            BAR;
        }
        // t == 17: fall through to epilogue

        const unsigned tmp = o0; o0 = o1; o1 = o2; o2 = tmp;
    }

    // ---- epilogue: C/D col=lane&15, row=(lane>>4)*4+reg; float4 stores ----
    const int c16 = l & 15;
    const int p4  = (l >> 4) << 2;
    #pragma unroll
    for (int mf = 0; mf < 6; ++mf) {
        const int m   = mb * BM + wr * 96 + mf * 16 + p4;
        const int n   = m / HW_OUT;
        const int rem = m - n * HW_OUT;
        float* ob = out + (size_t)n * CHW_OUT + rem;
        #pragma unroll
        for (int nf = 0; nf < 4; ++nf) {
            const int ch = wc * 64 + nf * 16 + c16;
            f32x4 v;
            #pragma unroll
            for (int j = 0; j < 4; ++j) v[j] = (float)acc[mf][nf][j];
            *(f32x4*)(ob + (size_t)ch * HW_OUT) = v;
        }
    }
    #undef STAGE_HALO
    #undef STAGE_B4
}

// -------- fallback (only if ws too small): naive direct conv, exact --------
__global__ __launch_bounds__(256) void conv_naive(const int* __restrict__ x,
                                                  const float* __restrict__ w,
                                                  float* __restrict__ out) {
    int idx = blockIdx.x * 256 + threadIdx.x;
    if (idx >= N_IMG * K_OUT * HW_OUT) return;
    const int wo = idx % W_OUT;
    int tmp = idx / W_OUT;
    const int ho = tmp % H_OUT; tmp /= H_OUT;
    const int k = tmp % K_OUT;
    const int n = tmp / K_OUT;
    float acc = 0.f;
    for (int c = 0; c < C_IN; ++c) {
        const int* xp = x + ((size_t)((n * C_IN + c) * H_IN + ho)) * W_IN + wo;
        const float* wp = w + ((size_t)(k * C_IN + c)) * 9;
        #pragma unroll
        for (int r = 0; r < 3; ++r)
            #pragma unroll
            for (int s = 0; s < 3; ++s) {
                int xv = xp[r * W_IN + s];
                xv = xv < 0 ? 0 : (xv > 7 ? 7 : xv);
                acc += (float)xv * (float)(int)wp[r * 3 + s];
            }
    }
    out[idx] = acc;
}

extern "C" void kernel_launch(void* const* d_in, const int* in_sizes, int n_in,
                              void* d_out, int out_size, void* d_ws, size_t ws_size,
                              hipStream_t stream) {
    const int*   x = (const int*)d_in[0];
    const float* w = (const float*)d_in[1];
    float* out = (float*)d_out;

    const size_t need = XT_BYTES + WT_BYTES;   // ~26.3 MB (halo OOB stays inside)
    if (ws_size >= need) {
        unsigned char* xt = (unsigned char*)d_ws;
        unsigned char* wt = (unsigned char*)((char*)d_ws + XT_BYTES);
        hipLaunchKernelGGL(xform, dim3(N_IMG * H_IN + K_OUT), dim3(256), 0, stream,
                           x, w, xt, wt);
        hipLaunchKernelGGL(conv_mfma, dim3(M_PIX / BM), dim3(512), 0, stream,
                           xt, wt, out);
    } else {
        const int total = N_IMG * K_OUT * HW_OUT;
        hipLaunchKernelGGL(conv_naive, dim3((total + 255) / 256), dim3(256), 0, stream, x, w, out);
    }
}

// Round 9
// 94.722 us; speedup vs baseline: 1.0960x; 1.0960x over previous
//
#include <hip/hip_runtime.h>
#include <stdint.h>

typedef int i32x4 __attribute__((ext_vector_type(4)));
typedef float f32x4 __attribute__((ext_vector_type(4)));

#define N_IMG 32
#define C_IN 256
#define H_IN 56
#define W_IN 56
#define K_OUT 256
#define H_OUT 54
#define W_OUT 54
#define HW_OUT 2916          // 54*54
#define M_PIX 93312          // 32*2916 = 192 * 486
#define CHW_OUT 746496       // 256*2916

#define BM 192               // pixel rows per block (grid 486)

#define XT_BYTES ((size_t)N_IMG * H_IN * W_IN * C_IN)   // 25,690,112 (i8 NHWC)
#define WT_BYTES ((size_t)9 * K_OUT * C_IN)             // 589,824

// -------- transforms --------
// xt: NCHW i32 -> NHWC i8 (clip 0..7)
// wt: OIHW f32 -> [tap][h][kk][o][g]x16B: one B-fragment = wave-contiguous 1KB.
//     (tap,h) stride 32768, kk stride 16384, o stride 64, g stride 16.
__global__ __launch_bounds__(256) void xform(const int* __restrict__ x,
                                             const float* __restrict__ w,
                                             unsigned char* __restrict__ xt,
                                             unsigned char* __restrict__ wt) {
    const int bid = blockIdx.x;
    if (bid < N_IMG * H_IN) {
        const int n = bid / H_IN;
        const int h = bid % H_IN;
        const int c = threadIdx.x;
        const int* src = x + ((size_t)((n * C_IN + c) * H_IN + h)) * W_IN;
        unsigned char* dst = xt + ((size_t)(n * H_IN + h) * W_IN) * C_IN + c;
        #pragma unroll
        for (int w0 = 0; w0 < W_IN; w0 += 4) {
            int4 v = *(const int4*)(src + w0);
            int a[4] = {v.x, v.y, v.z, v.w};
            #pragma unroll
            for (int j = 0; j < 4; ++j) {
                int q = a[j] < 0 ? 0 : (a[j] > 7 ? 7 : a[j]);
                dst[(size_t)(w0 + j) * C_IN] = (unsigned char)q;
            }
        }
    } else {
        const int o = bid - N_IMG * H_IN;     // out-channel
        const int c = threadIdx.x;            // in-channel
        const float* src = w + ((size_t)o * C_IN + c) * 9;
        const int h  = c >> 7;                // 128-half
        const int kk = (c >> 6) & 1;          // 64 within half
        const int g  = (c >> 4) & 3;          // 16-chunk within 64
        const int b  = c & 15;                // byte within 16
        #pragma unroll
        for (int rs = 0; rs < 9; ++rs) {
            int iv = (int)src[rs];   // truncation == astype(int32); values 0..6
            wt[(size_t)((rs * 2 + h) * 2 + kk) * 16384 + o * 64 + g * 16 + b]
                = (unsigned char)iv;
        }
    }
}

// -------- async global->LDS (width 16) --------
__device__ __forceinline__ void gload_lds16(const void* g, void* l) {
    __builtin_amdgcn_global_load_lds(
        (const __attribute__((address_space(1))) uint32_t*)g,
        (__attribute__((address_space(3))) uint32_t*)l,
        16, 0, 0);
}

// -------- main conv (i8): barrier-free wave-autonomous K-loop --------
// BM=192 pix x BN=256 ch; 8 waves (2M x 4N), per-wave 96x64, acc[6][4].
// A: halo LDS (448 rows x 128B, staged once per ch-half, both-sides swizzle).
// B: per-wave global->reg, double-buffered; 18 K-tiles (9 taps x 2 ch-halves).
__global__ __launch_bounds__(512, 2) void conv_mfma(const unsigned char* __restrict__ xt,
                                                    const unsigned char* __restrict__ wt,
                                                    float* __restrict__ out) {
    __shared__ __align__(16) unsigned char halo[57344];   // 448 x 128 B

    const int t512 = threadIdx.x;
    const int l    = t512 & 63;
    const int wid  = t512 >> 6;
    const int wr   = wid >> 2;     // 0..1 -> 96-pixel half
    const int wc   = wid & 3;      // 0..3 -> 64-channel quarter
    const int mb   = blockIdx.x;   // 486 M-tiles

    // halo staging geometry (proven both-sides swizzle): 8KB rounds of 64 rows
    const int slot = t512 & 7;
    const int srow = t512 >> 3;
    const int cs   = ((slot ^ (srow & 7)) << 4);
    const int tb16 = t512 * 16;
    const int sb   = srow * 256 + cs;

    // block-base input pixel
    const int m0  = mb * BM;
    const int n0  = m0 / HW_OUT;
    const int rm0 = m0 - n0 * HW_OUT;
    const int oh0 = rm0 / W_OUT;
    const int ow0 = rm0 - oh0 * W_OUT;
    const int pix0 = n0 * (H_IN * W_IN) + oh0 * W_IN + ow0;

    // per-lane halo row deltas for the 6 M-fragments
    const int lrow = l & 15;
    int drow[6];
    #pragma unroll
    for (int mf = 0; mf < 6; ++mf) {
        const int m   = m0 + wr * 96 + mf * 16 + lrow;
        const int n   = m / HW_OUT;
        const int rem = m - n * HW_OUT;
        const int oh  = rem / W_OUT;
        const int ow  = rem - oh * W_OUT;
        drow[mf] = n * (H_IN * W_IN) + oh * W_IN + ow - pix0;   // 0..~424 (<448-114)
    }

    const unsigned g16 = (unsigned)((l >> 4) << 4);   // 0/16/32/48

    // B fragment base: layout [tap][h][kk][o][g]x16B
    // addr(nf,kk;tap,h) = wb + (tap*2+h)*32768 + kk*16384
    //                     + (wc*64+nf*16+(l&15))*64 + (l>>4)*16
    const char* wb = (const char*)wt;
    const char* bptr[4];
    #pragma unroll
    for (int nf = 0; nf < 4; ++nf)
        bptr[nf] = wb + (wc * 64 + nf * 16 + (l & 15)) * 64 + (l >> 4) * 16;

    i32x4 acc[6][4];
    #pragma unroll
    for (int i = 0; i < 6; ++i)
        #pragma unroll
        for (int j = 0; j < 4; ++j)
            acc[i][j] = (i32x4){0, 0, 0, 0};

    const char* xb = (const char*)xt;

    #define STAGE_HALO(H) do {                                               \
        const char* hs_ = xb + (size_t)pix0 * 256 + (H) * 128 + sb;          \
        _Pragma("unroll")                                                    \
        for (int i_ = 0; i_ < 7; ++i_)                                       \
            gload_lds16(hs_ + (size_t)i_ * 16384, halo + i_ * 8192 + tb16);  \
    } while (0)

    // load one B tile (tap,h) into 8 regs: (tap,h) stride 32768, kk stride 16384
    #define LOADB(B, TAP, H) do {                                            \
        const int bo_ = ((TAP) * 2 + (H)) * 32768;                           \
        _Pragma("unroll")                                                    \
        for (int nf = 0; nf < 4; ++nf) {                                     \
            B[nf][0] = *(const i32x4*)(bptr[nf] + bo_);                      \
            B[nf][1] = *(const i32x4*)(bptr[nf] + bo_ + 16384);              \
        }                                                                    \
    } while (0)

    // compute one K-tile (tap) against B regs; A from halo
    #define TILE(B, TAP) do {                                                \
        const int toff_ = ((TAP) / 3) * W_IN + ((TAP) % 3);                  \
        _Pragma("unroll")                                                    \
        for (int kk = 0; kk < 2; ++kk) {                                     \
            i32x4 av_[6];                                                    \
            _Pragma("unroll")                                                \
            for (int mf = 0; mf < 6; ++mf) {                                 \
                const int row_ = drow[mf] + toff_;                           \
                const unsigned off_ = ((unsigned)row_ << 7) +                \
                    (((unsigned)(kk << 6) + g16) ^ ((unsigned)(row_ & 7) << 4)); \
                av_[mf] = *(const i32x4*)(halo + off_);                      \
            }                                                                \
            _Pragma("unroll")                                                \
            for (int mf = 0; mf < 6; ++mf)                                   \
                _Pragma("unroll")                                            \
                for (int nf = 0; nf < 4; ++nf)                               \
                    acc[mf][nf] = __builtin_amdgcn_mfma_i32_16x16x64_i8(     \
                        av_[mf], B[nf][kk], acc[mf][nf], 0, 0, 0);           \
        }                                                                    \
    } while (0)

    i32x4 b0[4][2], b1[4][2];

    // ---- prologue: halo(half 0) + B(tap 0, half 0) ----
    STAGE_HALO(0);
    LOADB(b0, 0, 0);
    asm volatile("s_waitcnt vmcnt(0)" ::: "memory");   // halo + b0 resident
    __builtin_amdgcn_s_barrier();

    // ---- segment 0: taps 0..8 on ch-half 0; barrier-free, each tap once ----
    #pragma unroll
    for (int t = 0; t < 8; t += 2) {
        LOADB(b1, t + 1, 0);
        TILE(b0, t);
        LOADB(b0, t + 2, 0);           // t+2 <= 8
        TILE(b1, t + 1);
    }
    LOADB(b1, 0, 1);                   // prefetch first tile of half 1
    TILE(b0, 8);

    // ---- halo restage (the only barriers in the kernel) ----
    __builtin_amdgcn_s_barrier();                      // all half-0 reads done
    STAGE_HALO(1);
    asm volatile("s_waitcnt vmcnt(0)" ::: "memory");
    __builtin_amdgcn_s_barrier();

    // ---- segment 1: taps 0..8 on ch-half 1 (b1 holds tap 0) ----
    #pragma unroll
    for (int t = 0; t < 8; t += 2) {
        LOADB(b0, t + 1, 1);
        TILE(b1, t);
        LOADB(b1, t + 2, 1);           // t+2 <= 8
        TILE(b0, t + 1);
    }
    TILE(b1, 8);

    // ---- epilogue: C/D col=lane&15, row=(lane>>4)*4+reg; float4 stores ----
    const int c16 = l & 15;
    const int p4  = (l >> 4) << 2;
    #pragma unroll
    for (int mf = 0; mf < 6; ++mf) {
        const int m   = mb * BM + wr * 96 + mf * 16 + p4;
        const int n   = m / HW_OUT;
        const int rem = m - n * HW_OUT;
        float* ob = out + (size_t)n * CHW_OUT + rem;
        #pragma unroll
        for (int nf = 0; nf < 4; ++nf) {
            const int ch = wc * 64 + nf * 16 + c16;
            f32x4 v;
            #pragma unroll
            for (int j = 0; j < 4; ++j) v[j] = (float)acc[mf][nf][j];
            *(f32x4*)(ob + (size_t)ch * HW_OUT) = v;
        }
    }
    #undef TILE
    #undef LOADB
    #undef STAGE_HALO
}

// -------- fallback (only if ws too small): naive direct conv, exact --------
__global__ __launch_bounds__(256) void conv_naive(const int* __restrict__ x,
                                                  const float* __restrict__ w,
                                                  float* __restrict__ out) {
    int idx = blockIdx.x * 256 + threadIdx.x;
    if (idx >= N_IMG * K_OUT * HW_OUT) return;
    const int wo = idx % W_OUT;
    int tmp = idx / W_OUT;
    const int ho = tmp % H_OUT; tmp /= H_OUT;
    const int k = tmp % K_OUT;
    const int n = tmp / K_OUT;
    float acc = 0.f;
    for (int c = 0; c < C_IN; ++c) {
        const int* xp = x + ((size_t)((n * C_IN + c) * H_IN + ho)) * W_IN + wo;
        const float* wp = w + ((size_t)(k * C_IN + c)) * 9;
        #pragma unroll
        for (int r = 0; r < 3; ++r)
            #pragma unroll
            for (int s = 0; s < 3; ++s) {
                int xv = xp[r * W_IN + s];
                xv = xv < 0 ? 0 : (xv > 7 ? 7 : xv);
                acc += (float)xv * (float)(int)wp[r * 3 + s];
            }
    }
    out[idx] = acc;
}

extern "C" void kernel_launch(void* const* d_in, const int* in_sizes, int n_in,
                              void* d_out, int out_size, void* d_ws, size_t ws_size,
                              hipStream_t stream) {
    const int*   x = (const int*)d_in[0];
    const float* w = (const float*)d_in[1];
    float* out = (float*)d_out;

    const size_t need = XT_BYTES + WT_BYTES;   // ~26.3 MB (halo OOB stays inside)
    if (ws_size >= need) {
        unsigned char* xt = (unsigned char*)d_ws;
        unsigned char* wt = (unsigned char*)((char*)d_ws + XT_BYTES);
        hipLaunchKernelGGL(xform, dim3(N_IMG * H_IN + K_OUT), dim3(256), 0, stream,
                           x, w, xt, wt);
        hipLaunchKernelGGL(conv_mfma, dim3(M_PIX / BM), dim3(512), 0, stream,
                           xt, wt, out);
    } else {
        const int total = N_IMG * K_OUT * HW_OUT;
        hipLaunchKernelGGL(conv_naive, dim3((total + 255) / 256), dim3(256), 0, stream, x, w, out);
    }
}